// Round 2
// baseline (404.193 us; speedup 1.0000x reference)
//
#include <hip/hip_runtime.h>

#define N_NODES 50000
#define N_EDGES 800000
#define IN_FEAT 512
#define OUT_FEAT 128

// NUMERICS CONTRACT (R3 post-mortem): the harness's np reference is matched
// bit-for-bit through the multispike quantizer ONLY when fp32 accumulation
// order is strictly sequential (k-order in GEMM, edge-order in SPMM).
// Reassociating a sum (R3's even/odd edge split) flipped a floor() boundary
// -> absmax 0.25. Do NOT split accumulator chains; get MLP from batched
// independent loads feeding ONE in-order FMA chain.
//
// R5 post-mortem: holding a 48-VGPR prefetch set across the compute spilled
// to scratch (WRITE_SIZE +19MB, VALUBusy 33->26, dur +44us). Do NOT hold
// large prefetch arrays in registers across the FMA block.

__device__ __forceinline__ float multispike(float a) {
    // floor(clamp(4x, 0, 4) + 0.5) / 4
    return floorf(fminf(fmaxf(4.0f * a, 0.0f), 4.0f) + 0.5f) * 0.25f;
}

// ---------------------------------------------------------------------------
// GEMM: C[M,128] = A[M,512] @ B[512,128], fp32 vector FMA.
// BM=64, BN=128, BK=32. 128 threads (2 waves). Thread tile 8x8.
//
// R6 restructure (LDS-pipe relief): R4's counters showed the CU's LDS pipe
// was the critical resource (~10.4k cyc/chunk vs 6.1k VALU) plus 2.1k
// cyc/chunk of A-transpose-store bank conflicts (SQ_LDS_BANK_CONFLICT 8.8M).
// A has no cross-wave reuse (BN=128 covers all of N; each 16B A-chunk feeds
// exactly one 16-lane broadcast read), so A now bypasses LDS entirely:
// each thread reads its 8 rows as float4 (4 k's) straight from global (L1
// broadcast, separate pipe from LDS). B keeps LDS but is double-buffered
// and staged via global_load_lds (zero staging VGPRs -> no spill risk;
// issued BEFORE the compute so the pre-barrier vmcnt(0) drain hits
// completed loads). Only a 32-VGPR one-group A prefetch (an[8]) crosses the
// chunk boundary, killing the chunk-start bubble.
// - Bs XOR quad-swizzle pq = q ^ ((q>>3)&1) kept on the READ side; the
//   STORE side is linear (global_load_lds requirement) with the inverse
//   swizzle applied to the per-lane GLOBAL source address (involution, so
//   same map; see rule "both-sides-or-neither", m104/m231).
// - Accumulation: per acc[i][j] the fmaf chain runs k = 0..511 strictly
//   ascending, identical to R4 -> bit-exact.
// ---------------------------------------------------------------------------
__device__ __forceinline__ int bswz(int q) { return q ^ ((q >> 3) & 1); }

__global__ __launch_bounds__(128, 2) void gemm_kernel(const float* __restrict__ A,
                                                      const float* __restrict__ B,
                                                      float* __restrict__ C, int M) {
    __shared__ float Bs[2][32][128];   // double-buffered, quad-swizzled storage

    const int tid = threadIdx.x;
    const int tx = tid & 15;   // n0 = tx*8
    const int ty = tid >> 4;   // m0 = ty*8  (0..7)
    const int block_m = blockIdx.x * 64;

    // read-side physical quads for this thread's two B float4s
    const int bq0 = bswz(2 * tx) * 4;
    const int bq1 = bswz(2 * tx + 1) * 4;

    // A row pointers; OOB rows clamp to row 0 (their acc is never stored).
    const float* arow[8];
#pragma unroll
    for (int i = 0; i < 8; i++) {
        int gm = block_m + ty * 8 + i;
        arow[i] = A + (size_t)(gm < M ? gm : 0) * IN_FEAT;
    }

    float acc[8][8];
#pragma unroll
    for (int i = 0; i < 8; i++)
#pragma unroll
        for (int j = 0; j < 8; j++) acc[i][j] = 0.0f;

    // Stage one B K-tile (32x128 = 1024 16B-granules / 128 thr = 8 each)
    // into Bs[buf] via global_load_lds. LDS dest is LINEAR in the lane
    // (slot s = tid + i*128, byte = s*16 -> wave-uniform base + lane*16);
    // physical slot (r, p) receives B[k0+r][bswz(p)*4..+3] so the swizzled
    // READ Bs[k][bswz(q)*4] returns logical quad q.
    auto stage = [&](int buf, int k0) {
#pragma unroll
        for (int i = 0; i < 8; i++) {
            int s = tid + i * 128;
            int r = s >> 5;             // 0..31
            int p = s & 31;             // physical quad
            const float* src = B + (size_t)(k0 + r) * OUT_FEAT + bswz(p) * 4;
            float* dst = &Bs[buf][0][0] + (size_t)s * 4;
            __builtin_amdgcn_global_load_lds(
                (const __attribute__((address_space(1))) void*)src,
                (__attribute__((address_space(3))) void*)dst, 16, 0, 0);
        }
    };

    // ---- prologue: stage B tile 0, prefetch A group (t=0, kq=0)
    stage(0, 0);
    float4 an[8];
#pragma unroll
    for (int i = 0; i < 8; i++) an[i] = *(const float4*)(arow[i]);
    __syncthreads();   // vmcnt(0)+lgkmcnt(0) drain -> Bs[0] and an[] ready

    for (int t = 0; t < 16; t++) {
        const int k0 = t * 32;
        const int cur = t & 1;

        // issue next B tile into the other buffer; latency hides under the
        // 2048 FMAs below, drained by the barrier at the end of this iter.
        if (t < 15) stage(cur ^ 1, k0 + 32);

        // kq=0 uses the prefetched an[]; immediately re-issue an[] for the
        // next chunk (consumed next iteration, done by barrier time).
        float4 a0[8];
#pragma unroll
        for (int i = 0; i < 8; i++) a0[i] = an[i];
        if (t < 15) {
#pragma unroll
            for (int i = 0; i < 8; i++)
                an[i] = *(const float4*)(arow[i] + k0 + 32);
        }

#pragma unroll
        for (int kq = 0; kq < 8; kq++) {
            float4 a[8];
            if (kq == 0) {
#pragma unroll
                for (int i = 0; i < 8; i++) a[i] = a0[i];
            } else {
#pragma unroll
                for (int i = 0; i < 8; i++)
                    a[i] = *(const float4*)(arow[i] + k0 + kq * 4);
            }
#pragma unroll
            for (int kk = 0; kk < 4; kk++) {
                const int k = kq * 4 + kk;
                float4 b0 = *(const float4*)&Bs[cur][k][bq0];
                float4 b1 = *(const float4*)&Bs[cur][k][bq1];
                float bvv[8] = {b0.x, b0.y, b0.z, b0.w, b1.x, b1.y, b1.z, b1.w};
                float avv[8];
#pragma unroll
                for (int i = 0; i < 8; i++)   // kk is a compile-time constant
                    avv[i] = (kk == 0) ? a[i].x : (kk == 1) ? a[i].y
                           : (kk == 2) ? a[i].z : a[i].w;
#pragma unroll
                for (int i = 0; i < 8; i++)
#pragma unroll
                    for (int j = 0; j < 8; j++)
                        acc[i][j] = fmaf(avv[i], bvv[j], acc[i][j]);
            }
        }
        __syncthreads();   // drains vmcnt -> next B tile ready; guards buffer reuse
    }

#pragma unroll
    for (int i = 0; i < 8; i++) {
        int gm = block_m + ty * 8 + i;
        if (gm < M) {
            float* cp = C + (size_t)gm * OUT_FEAT + tx * 8;
            *(float4*)cp = make_float4(acc[i][0], acc[i][1], acc[i][2], acc[i][3]);
            *(float4*)(cp + 4) = make_float4(acc[i][4], acc[i][5], acc[i][6], acc[i][7]);
        }
    }
}

// ---------------------------------------------------------------------------
// row_ptr[i] = lower_bound(rows, i) over sorted rows. i in [0, N_NODES].
// ---------------------------------------------------------------------------
__global__ __launch_bounds__(256) void rowptr_kernel(const int* __restrict__ rows,
                                                     int* __restrict__ row_ptr) {
    int i = blockIdx.x * blockDim.x + threadIdx.x;
    if (i > N_NODES) return;
    int lo = 0, hi = N_EDGES;
    while (lo < hi) {
        int mid = (lo + hi) >> 1;
        if (rows[mid] < i) lo = mid + 1; else hi = mid;
    }
    row_ptr[i] = lo;
}

// ---------------------------------------------------------------------------
// SPMM + multispike: one wave per output row, lane l owns float2 l of the
// 128-float row. Unroll x8: 8 independent gathers issued per step (MLP),
// then ONE in-order FMA chain per accumulator -> summation order identical
// to the reference edge order (see NUMERICS CONTRACT above).
// ---------------------------------------------------------------------------
__global__ __launch_bounds__(256) void spmm_kernel(const float* __restrict__ x,
                                                   const int* __restrict__ cols,
                                                   const float* __restrict__ ew,
                                                   const int* __restrict__ row_ptr,
                                                   float* __restrict__ out) {
    const int wave = threadIdx.x >> 6;
    const int lane = threadIdx.x & 63;
    const int r = blockIdx.x * 4 + wave;
    if (r >= N_NODES) return;

    const int e0 = row_ptr[r];
    const int e1 = row_ptr[r + 1];
    const float2* __restrict__ x2 = (const float2*)x;

    float accx = 0.0f, accy = 0.0f;
    int e = e0;
    for (; e + 8 <= e1; e += 8) {
        int c[8];
        float w[8];
        float2 v[8];
#pragma unroll
        for (int j = 0; j < 8; j++) {
            c[j] = cols[e + j];
            w[j] = ew[e + j];
        }
#pragma unroll
        for (int j = 0; j < 8; j++) {
            v[j] = x2[(size_t)c[j] * 64 + lane];
        }
#pragma unroll
        for (int j = 0; j < 8; j++) {   // strict e-order accumulation
            accx = fmaf(w[j], v[j].x, accx);
            accy = fmaf(w[j], v[j].y, accy);
        }
    }
    for (; e < e1; e++) {
        int c = cols[e];
        float w = ew[e];
        float2 v = x2[(size_t)c * 64 + lane];
        accx = fmaf(w, v.x, accx);
        accy = fmaf(w, v.y, accy);
    }
    float2* out2 = (float2*)out;
    out2[(size_t)r * 64 + lane] = make_float2(multispike(accx), multispike(accy));
}

extern "C" void kernel_launch(void* const* d_in, const int* in_sizes, int n_in,
                              void* d_out, int out_size, void* d_ws, size_t ws_size,
                              hipStream_t stream) {
    const float* feat = (const float*)d_in[0];   // [50000, 512]
    const float* weight = (const float*)d_in[1]; // [512, 128]
    const int* rows = (const int*)d_in[2];       // [800000] sorted
    const int* cols = (const int*)d_in[3];       // [800000]
    const float* ew = (const float*)d_in[4];     // [800000]
    float* out = (float*)d_out;                  // [50000, 128]

    // Workspace layout: x [50000*128 f32] then row_ptr [50001 i32]
    float* x = (float*)d_ws;
    int* row_ptr = (int*)((char*)d_ws + (size_t)N_NODES * OUT_FEAT * sizeof(float));

    rowptr_kernel<<<(N_NODES + 256) / 256, 256, 0, stream>>>(rows, row_ptr);
    gemm_kernel<<<(N_NODES + 63) / 64, 128, 0, stream>>>(feat, weight, x, N_NODES);
    spmm_kernel<<<(N_NODES + 3) / 4, 256, 0, stream>>>(x, cols, ew, row_ptr, out);
}

// Round 3
// 330.627 us; speedup vs baseline: 1.2225x; 1.2225x over previous
//
#include <hip/hip_runtime.h>

#define N_NODES 50000
#define N_EDGES 800000
#define IN_FEAT 512
#define OUT_FEAT 128

// NUMERICS CONTRACT (R3 post-mortem): the harness's np reference is matched
// bit-for-bit through the multispike quantizer ONLY when fp32 accumulation
// order is strictly sequential (k-order in GEMM, edge-order in SPMM).
// Reassociating a sum flipped a floor() boundary -> absmax 0.25. Do NOT
// split accumulator chains.
//
// R5/R6 post-mortem (HARD RULE): with acc[8][8] (64 VGPR) resident, any
// additional multi-float4 register array held across a loop boundary
// spills to scratch (R5: +19MB writes; R6: +91MB writes, VALUBusy 22%).
// All staging must be zero-register: global_load_lds DMA only.

__device__ __forceinline__ float multispike(float a) {
    // floor(clamp(4x, 0, 4) + 0.5) / 4
    return floorf(fminf(fmaxf(4.0f * a, 0.0f), 4.0f) + 0.5f) * 0.25f;
}

// ---------------------------------------------------------------------------
// GEMM: C[M,128] = A[M,512] @ B[512,128], fp32 vector FMA.
// BM=64, BN=128, BK=32. 128 threads (2 waves). Thread tile 8x8.
//
// R7: both A and B staged via global_load_lds (zero staging VGPRs), double
// buffered; DMA for chunk t+1 issued before chunk t's 2048 FMAs, drained by
// the compiler's vmcnt(0) at the end-of-iteration barrier. This removes
// R4's three overheads at once: the transposed A-store bank conflicts
// (8.8M), ~24 staging LDS-write instrs/thread/chunk on the LDS pipe, and
// the barrier-exposed global latency (only ~1.5 waves/SIMD of TLP here).
//
// A layout: As[m][k] row-major (DMA dest must be lane-linear), with XOR
// swizzle on the K-QUAD: physical quad = kq ^ (m>>3), applied identically
// to the DMA *source* address and the LDS read (both-sides-or-neither,
// m104/m231). Read check: a[i] = As[ty*8+i][(kq^ty)*4], per wave 4 distinct
// m (128B stride, all bank-0 unswizzled) get 4 distinct XOR values -> 4
// distinct banks -> conflict-free; 16 same-ty lanes broadcast.
// B layout: Bs[k][n] with quad swizzle bswz(q)=q^((q>>3)&1) on source and
// read (R4-verified, 2-way = free).
// Accumulation: per acc[i][j] the fmaf chain runs k=0..511 strictly
// ascending (kq-major, kk-minor), identical to R4 -> bit-exact.
// ---------------------------------------------------------------------------
__device__ __forceinline__ int bswz(int q) { return q ^ ((q >> 3) & 1); }

__global__ __launch_bounds__(128) void gemm_kernel(const float* __restrict__ A,
                                                   const float* __restrict__ B,
                                                   float* __restrict__ C, int M) {
    __shared__ float As[2][64][32];    // [buf][m][k], quad-swizzled in k
    __shared__ float Bs[2][32][128];   // [buf][k][n], quad-swizzled in n

    const int tid = threadIdx.x;
    const int tx = tid & 15;   // n0 = tx*8
    const int ty = tid >> 4;   // m0 = ty*8  (0..7)
    const int block_m = blockIdx.x * 64;

    // read-side physical quads for this thread's two B float4s
    const int bq0 = bswz(2 * tx) * 4;
    const int bq1 = bswz(2 * tx + 1) * 4;

    float acc[8][8];
#pragma unroll
    for (int i = 0; i < 8; i++)
#pragma unroll
        for (int j = 0; j < 8; j++) acc[i][j] = 0.0f;

    // Zero-register staging of one K-chunk (A: 64x32, B: 32x128) via DMA.
    // LDS dest is linear in the flat slot s (wave-uniform base + lane*16);
    // the swizzles are applied to the per-lane GLOBAL source address.
    auto stage = [&](int buf, int k0) {
        // A: 512 16B-granules / 128 threads = 4 each. slot s -> (m = s>>3,
        // phys quad p = s&7) which must hold logical quad kq = p ^ (m>>3).
#pragma unroll
        for (int i = 0; i < 4; i++) {
            int s = tid + i * 128;
            int m = s >> 3;
            int p = s & 7;
            int gm = block_m + m;
            if (gm >= M) gm = M - 1;          // clamp; data never consumed
            int kq = p ^ (m >> 3);
            const float* src = A + (size_t)gm * IN_FEAT + k0 + kq * 4;
            float* dst = &As[buf][0][0] + (size_t)s * 4;
            __builtin_amdgcn_global_load_lds(
                (const __attribute__((address_space(1))) void*)src,
                (__attribute__((address_space(3))) void*)dst, 16, 0, 0);
        }
        // B: 1024 granules / 128 threads = 8 each. slot s -> (r = s>>5,
        // phys quad p = s&31) holds logical quad bswz(p) (involution).
#pragma unroll
        for (int i = 0; i < 8; i++) {
            int s = tid + i * 128;
            int r = s >> 5;
            int p = s & 31;
            const float* src = B + (size_t)(k0 + r) * OUT_FEAT + bswz(p) * 4;
            float* dst = &Bs[buf][0][0] + (size_t)s * 4;
            __builtin_amdgcn_global_load_lds(
                (const __attribute__((address_space(1))) void*)src,
                (__attribute__((address_space(3))) void*)dst, 16, 0, 0);
        }
    };

    // ---- prologue: stage chunk 0; barrier drains vmcnt
    stage(0, 0);
    __syncthreads();

    for (int t = 0; t < 16; t++) {
        const int cur = t & 1;

        // issue DMA for chunk t+1 into the other buffer; its latency hides
        // under the 2048 FMAs below and is drained by the barrier.
        if (t < 15) stage(cur ^ 1, (t + 1) * 32);

#pragma unroll
        for (int kq = 0; kq < 8; kq++) {
            const int pq = (kq ^ ty) * 4;   // A read-side swizzle
            float4 a[8];
#pragma unroll
            for (int i = 0; i < 8; i++)
                a[i] = *(const float4*)&As[cur][ty * 8 + i][pq];
#pragma unroll
            for (int kk = 0; kk < 4; kk++) {
                const int k = kq * 4 + kk;
                float4 b0 = *(const float4*)&Bs[cur][k][bq0];
                float4 b1 = *(const float4*)&Bs[cur][k][bq1];
                float bvv[8] = {b0.x, b0.y, b0.z, b0.w, b1.x, b1.y, b1.z, b1.w};
                float avv[8];
#pragma unroll
                for (int i = 0; i < 8; i++)   // kk is compile-time constant
                    avv[i] = (kk == 0) ? a[i].x : (kk == 1) ? a[i].y
                           : (kk == 2) ? a[i].z : a[i].w;
#pragma unroll
                for (int i = 0; i < 8; i++)
#pragma unroll
                    for (int j = 0; j < 8; j++)
                        acc[i][j] = fmaf(avv[i], bvv[j], acc[i][j]);
            }
        }
        __syncthreads();   // vmcnt(0) drain: next chunk's DMA complete; guards buf reuse
    }

#pragma unroll
    for (int i = 0; i < 8; i++) {
        int gm = block_m + ty * 8 + i;
        if (gm < M) {
            float* cp = C + (size_t)gm * OUT_FEAT + tx * 8;
            *(float4*)cp = make_float4(acc[i][0], acc[i][1], acc[i][2], acc[i][3]);
            *(float4*)(cp + 4) = make_float4(acc[i][4], acc[i][5], acc[i][6], acc[i][7]);
        }
    }
}

// ---------------------------------------------------------------------------
// row_ptr[i] = lower_bound(rows, i) over sorted rows. i in [0, N_NODES].
// ---------------------------------------------------------------------------
__global__ __launch_bounds__(256) void rowptr_kernel(const int* __restrict__ rows,
                                                     int* __restrict__ row_ptr) {
    int i = blockIdx.x * blockDim.x + threadIdx.x;
    if (i > N_NODES) return;
    int lo = 0, hi = N_EDGES;
    while (lo < hi) {
        int mid = (lo + hi) >> 1;
        if (rows[mid] < i) lo = mid + 1; else hi = mid;
    }
    row_ptr[i] = lo;
}

// ---------------------------------------------------------------------------
// SPMM + multispike: one wave per output row, lane l owns float2 l of the
// 128-float row. Unroll x8: 8 independent gathers issued per step (MLP),
// then ONE in-order FMA chain per accumulator -> summation order identical
// to the reference edge order (see NUMERICS CONTRACT above).
// ---------------------------------------------------------------------------
__global__ __launch_bounds__(256) void spmm_kernel(const float* __restrict__ x,
                                                   const int* __restrict__ cols,
                                                   const float* __restrict__ ew,
                                                   const int* __restrict__ row_ptr,
                                                   float* __restrict__ out) {
    const int wave = threadIdx.x >> 6;
    const int lane = threadIdx.x & 63;
    const int r = blockIdx.x * 4 + wave;
    if (r >= N_NODES) return;

    const int e0 = row_ptr[r];
    const int e1 = row_ptr[r + 1];
    const float2* __restrict__ x2 = (const float2*)x;

    float accx = 0.0f, accy = 0.0f;
    int e = e0;
    for (; e + 8 <= e1; e += 8) {
        int c[8];
        float w[8];
        float2 v[8];
#pragma unroll
        for (int j = 0; j < 8; j++) {
            c[j] = cols[e + j];
            w[j] = ew[e + j];
        }
#pragma unroll
        for (int j = 0; j < 8; j++) {
            v[j] = x2[(size_t)c[j] * 64 + lane];
        }
#pragma unroll
        for (int j = 0; j < 8; j++) {   // strict e-order accumulation
            accx = fmaf(w[j], v[j].x, accx);
            accy = fmaf(w[j], v[j].y, accy);
        }
    }
    for (; e < e1; e++) {
        int c = cols[e];
        float w = ew[e];
        float2 v = x2[(size_t)c * 64 + lane];
        accx = fmaf(w, v.x, accx);
        accy = fmaf(w, v.y, accy);
    }
    float2* out2 = (float2*)out;
    out2[(size_t)r * 64 + lane] = make_float2(multispike(accx), multispike(accy));
}

extern "C" void kernel_launch(void* const* d_in, const int* in_sizes, int n_in,
                              void* d_out, int out_size, void* d_ws, size_t ws_size,
                              hipStream_t stream) {
    const float* feat = (const float*)d_in[0];   // [50000, 512]
    const float* weight = (const float*)d_in[1]; // [512, 128]
    const int* rows = (const int*)d_in[2];       // [800000] sorted
    const int* cols = (const int*)d_in[3];       // [800000]
    const float* ew = (const float*)d_in[4];     // [800000]
    float* out = (float*)d_out;                  // [50000, 128]

    // Workspace layout: x [50000*128 f32] then row_ptr [50001 i32]
    float* x = (float*)d_ws;
    int* row_ptr = (int*)((char*)d_ws + (size_t)N_NODES * OUT_FEAT * sizeof(float));

    rowptr_kernel<<<(N_NODES + 256) / 256, 256, 0, stream>>>(rows, row_ptr);
    gemm_kernel<<<(N_NODES + 63) / 64, 128, 0, stream>>>(feat, weight, x, N_NODES);
    spmm_kernel<<<(N_NODES + 3) / 4, 256, 0, stream>>>(x, cols, ew, row_ptr, out);
}

// Round 4
// 315.295 us; speedup vs baseline: 1.2820x; 1.0486x over previous
//
#include <hip/hip_runtime.h>

#define N_NODES 50000
#define N_EDGES 800000
#define IN_FEAT 512
#define OUT_FEAT 128

// NUMERICS CONTRACT (R3 post-mortem): the harness's np reference is matched
// bit-for-bit through the multispike quantizer ONLY when fp32 accumulation
// order is strictly sequential (k-order in GEMM, edge-order in SPMM).
// Reassociating a sum flipped a floor() boundary -> absmax 0.25. Do NOT
// split accumulator chains. Zero-padding with w=0 is safe: fmaf(0,v,acc)
// == acc bit-exactly for finite v.
//
// R5/R6 post-mortem (HARD RULE): with acc[8][8] resident, any additional
// multi-float4 register array held across a loop boundary spills.
// R7 post-mortem: single-barrier DMA double-buffer (48KB LDS, 3 blocks/CU)
// hides latency WORSE than the 2-barrier R4 loop with 6-blocks/CU capacity
// and cross-block overlap (180 vs 140us, VALUBusy 27 vs 33%). GEMM is
// reverted to the measured-best R4 structure; do not restructure it again
// without new counter evidence.

__device__ __forceinline__ float multispike(float a) {
    // floor(clamp(4x, 0, 4) + 0.5) / 4
    return floorf(fminf(fmaxf(4.0f * a, 0.0f), 4.0f) + 0.5f) * 0.25f;
}

// ---------------------------------------------------------------------------
// GEMM: C[M,128] = A[M,512] @ B[512,128], fp32 vector FMA.
// R4 structure VERBATIM (measured 140.9us, VALUBusy 33%, best of 4 variants).
// BM=64, BN=128, BK=32. 128 threads (2 waves). Thread tile 8x8.
// - As padded to 68: transposed-store 8-way conflict -> 4-way, rows stay
//   16B-aligned for b128 reads.
// - Bs XOR quad-swizzle pq = q ^ ((q>>3)&1): B-read 128B-stride aliasing
//   2-way = free (m136). Same map on store and load.
// ---------------------------------------------------------------------------
__device__ __forceinline__ int bswz(int q) { return q ^ ((q >> 3) & 1); }

__global__ __launch_bounds__(128) void gemm_kernel(const float* __restrict__ A,
                                                   const float* __restrict__ B,
                                                   float* __restrict__ C, int M) {
    __shared__ float As[32][68];    // [k][m], padded
    __shared__ float Bs[32][128];   // [k][n], quad-swizzled

    const int tid = threadIdx.x;
    const int tx = tid & 15;   // n0 = tx*8
    const int ty = tid >> 4;   // m0 = ty*8  (0..7)
    const int block_m = blockIdx.x * 64;

    const int bq0 = bswz(2 * tx) * 4;
    const int bq1 = bswz(2 * tx + 1) * 4;

    float acc[8][8];
#pragma unroll
    for (int i = 0; i < 8; i++)
#pragma unroll
        for (int j = 0; j < 8; j++) acc[i][j] = 0.0f;

    for (int k0 = 0; k0 < IN_FEAT; k0 += 32) {
        // Stage A tile: 64 rows x 32 k = 512 float4 / 128 threads = 4 each.
#pragma unroll
        for (int i = 0; i < 4; i++) {
            int f = tid + i * 128;
            int r = f >> 3;
            int kq = (f & 7) << 2;
            int gm = block_m + r;
            float4 v = make_float4(0.f, 0.f, 0.f, 0.f);
            if (gm < M) v = *(const float4*)(A + (size_t)gm * IN_FEAT + k0 + kq);
            As[kq + 0][r] = v.x;
            As[kq + 1][r] = v.y;
            As[kq + 2][r] = v.z;
            As[kq + 3][r] = v.w;
        }
        // Stage B tile: 32 rows x 128 n = 1024 float4 / 128 threads = 8 each.
#pragma unroll
        for (int i = 0; i < 8; i++) {
            int f = tid + i * 128;
            int r = f >> 5;
            int q = f & 31;
            *(float4*)&Bs[r][bswz(q) * 4] =
                *(const float4*)(B + (size_t)(k0 + r) * OUT_FEAT + q * 4);
        }
        __syncthreads();

#pragma unroll
        for (int k = 0; k < 32; k++) {
            float4 a0 = *(const float4*)&As[k][ty * 8];
            float4 a1 = *(const float4*)&As[k][ty * 8 + 4];
            float4 b0 = *(const float4*)&Bs[k][bq0];
            float4 b1 = *(const float4*)&Bs[k][bq1];
            float av[8] = {a0.x, a0.y, a0.z, a0.w, a1.x, a1.y, a1.z, a1.w};
            float bv[8] = {b0.x, b0.y, b0.z, b0.w, b1.x, b1.y, b1.z, b1.w};
#pragma unroll
            for (int i = 0; i < 8; i++)
#pragma unroll
                for (int j = 0; j < 8; j++)
                    acc[i][j] = fmaf(av[i], bv[j], acc[i][j]);
        }
        __syncthreads();
    }

#pragma unroll
    for (int i = 0; i < 8; i++) {
        int gm = block_m + ty * 8 + i;
        if (gm < M) {
            float* cp = C + (size_t)gm * OUT_FEAT + tx * 8;
            *(float4*)cp = make_float4(acc[i][0], acc[i][1], acc[i][2], acc[i][3]);
            *(float4*)(cp + 4) = make_float4(acc[i][4], acc[i][5], acc[i][6], acc[i][7]);
        }
    }
}

// ---------------------------------------------------------------------------
// row_ptr[i] = lower_bound(rows, i) over sorted rows. i in [0, N_NODES].
// ---------------------------------------------------------------------------
__global__ __launch_bounds__(256) void rowptr_kernel(const int* __restrict__ rows,
                                                     int* __restrict__ row_ptr) {
    int i = blockIdx.x * blockDim.x + threadIdx.x;
    if (i > N_NODES) return;
    int lo = 0, hi = N_EDGES;
    while (lo < hi) {
        int mid = (lo + hi) >> 1;
        if (rows[mid] < i) lo = mid + 1; else hi = mid;
    }
    row_ptr[i] = lo;
}

// ---------------------------------------------------------------------------
// SPMM + multispike: one wave per output row, lane l owns float2 l of the
// 128-float row.
// R8: the scalar tail loop (avg 4 edges/row, one serial ~300-900cy vmem
// chain per edge) is replaced by ZERO-PADDED unrolled-8 iterations: padded
// slots use clamped index + w=0, and fmaf(0,v,acc)==acc bit-exactly, so
// the live-edge accumulation order is unchanged (NUMERICS CONTRACT holds).
// Index loads for iteration t+1 are issued between the gathers and the FMA
// chain of iteration t, so the idx-load latency overlaps the gather wait
// instead of serializing in front of the next gather burst.
// ---------------------------------------------------------------------------
__global__ __launch_bounds__(256) void spmm_kernel(const float* __restrict__ x,
                                                   const int* __restrict__ cols,
                                                   const float* __restrict__ ew,
                                                   const int* __restrict__ row_ptr,
                                                   float* __restrict__ out) {
    const int wave = threadIdx.x >> 6;
    const int lane = threadIdx.x & 63;
    const int r = blockIdx.x * 4 + wave;
    if (r >= N_NODES) return;

    const int e0 = row_ptr[r];
    const int e1 = row_ptr[r + 1];
    const int niter = (e1 - e0 + 7) >> 3;   // zero-padded to multiple of 8
    const float2* __restrict__ x2 = (const float2*)x;

    float accx = 0.0f, accy = 0.0f;

    int c[8];
    float w[8];
    // prefetch indices for iteration 0 (clamped + zero-weighted past e1)
#pragma unroll
    for (int j = 0; j < 8; j++) {
        int e = e0 + j;
        int ee = (e < e1) ? e : (e1 - 1);
        c[j] = (niter > 0) ? cols[ee] : 0;
        w[j] = (e < e1) ? ew[ee] : 0.0f;
    }

    for (int t = 0; t < niter; t++) {
        // issue the 8 gathers for iteration t (independent -> MLP 8)
        float2 v[8];
#pragma unroll
        for (int j = 0; j < 8; j++) {
            v[j] = x2[(size_t)c[j] * 64 + lane];
        }
        // prefetch indices for iteration t+1; latency overlaps gather wait
        int cn[8];
        float wn[8];
        if (t + 1 < niter) {
            const int base = e0 + (t + 1) * 8;
#pragma unroll
            for (int j = 0; j < 8; j++) {
                int e = base + j;
                int ee = (e < e1) ? e : (e1 - 1);
                cn[j] = cols[ee];
                wn[j] = (e < e1) ? ew[ee] : 0.0f;
            }
        } else {
#pragma unroll
            for (int j = 0; j < 8; j++) { cn[j] = 0; wn[j] = 0.0f; }
        }
        // strict e-order accumulation (padded slots are exact no-ops)
#pragma unroll
        for (int j = 0; j < 8; j++) {
            accx = fmaf(w[j], v[j].x, accx);
            accy = fmaf(w[j], v[j].y, accy);
        }
#pragma unroll
        for (int j = 0; j < 8; j++) { c[j] = cn[j]; w[j] = wn[j]; }
    }

    float2* out2 = (float2*)out;
    out2[(size_t)r * 64 + lane] = make_float2(multispike(accx), multispike(accy));
}

extern "C" void kernel_launch(void* const* d_in, const int* in_sizes, int n_in,
                              void* d_out, int out_size, void* d_ws, size_t ws_size,
                              hipStream_t stream) {
    const float* feat = (const float*)d_in[0];   // [50000, 512]
    const float* weight = (const float*)d_in[1]; // [512, 128]
    const int* rows = (const int*)d_in[2];       // [800000] sorted
    const int* cols = (const int*)d_in[3];       // [800000]
    const float* ew = (const float*)d_in[4];     // [800000]
    float* out = (float*)d_out;                  // [50000, 128]

    // Workspace layout: x [50000*128 f32] then row_ptr [50001 i32]
    float* x = (float*)d_ws;
    int* row_ptr = (int*)((char*)d_ws + (size_t)N_NODES * OUT_FEAT * sizeof(float));

    rowptr_kernel<<<(N_NODES + 256) / 256, 256, 0, stream>>>(rows, row_ptr);
    gemm_kernel<<<(N_NODES + 63) / 64, 128, 0, stream>>>(feat, weight, x, N_NODES);
    spmm_kernel<<<(N_NODES + 3) / 4, 256, 0, stream>>>(x, cols, ew, row_ptr, out);
}

// Round 5
// 312.547 us; speedup vs baseline: 1.2932x; 1.0088x over previous
//
#include <hip/hip_runtime.h>

#define N_NODES 50000
#define N_EDGES 800000
#define IN_FEAT 512
#define OUT_FEAT 128

#define GEMM_BLOCKS ((N_NODES + 63) / 64)            // 782
#define ROWPTR_BLOCKS ((N_NODES + 1 + 127) / 128)    // 391 blocks of 128 thr

// NUMERICS CONTRACT (R3 post-mortem): the harness's np reference is matched
// bit-for-bit through the multispike quantizer ONLY when fp32 accumulation
// order is strictly sequential (k-order in GEMM, edge-order in SPMM).
// Reassociating a sum flipped a floor() boundary -> absmax 0.25. Do NOT
// split accumulator chains. Zero-padding with w=0 is safe: fmaf(0,v,acc)
// == acc bit-exactly for finite v.
//
// R5/R6 post-mortem (HARD RULE): with acc[8][8] resident, any additional
// multi-float4 register array held across a loop boundary spills.
// R7 post-mortem: GEMM restructures (reg-prefetch, A-direct, DMA dbuf) all
// lost to the plain R4 2-barrier loop (140.9us). GEMM is FROZEN.
// R8 post-mortem: spmm tail zero-padding ~neutral (318->315): tail
// serialization was not the spmm bottleneck. spmm ~135us ~= 3 TB/s gather.
// R9: probe spmm's regime - 16-deep gather pipeline (latency-bound -> ~2x;
// queue/fabric-BW-bound -> neutral and spmm is at its ceiling). rowptr
// fused into the gemm launch (independent inputs; saves a launch).

__device__ __forceinline__ float multispike(float a) {
    // floor(clamp(4x, 0, 4) + 0.5) / 4
    return floorf(fminf(fmaxf(4.0f * a, 0.0f), 4.0f) + 0.5f) * 0.25f;
}

// ---------------------------------------------------------------------------
// GEMM (R4 structure VERBATIM, measured 140.9us) + fused row_ptr blocks.
// Blocks [0, GEMM_BLOCKS): C[M,128] = A[M,512] @ B[512,128], fp32 FMA.
// Blocks [GEMM_BLOCKS, GEMM_BLOCKS+ROWPTR_BLOCKS): row_ptr[i] =
//   lower_bound(rows, i). These blocks return before any barrier (whole
//   block exits together -> no sync hazard) and free their CU slots in ~4us.
// ---------------------------------------------------------------------------
__device__ __forceinline__ int bswz(int q) { return q ^ ((q >> 3) & 1); }

__global__ __launch_bounds__(128) void gemm_rowptr_kernel(
    const float* __restrict__ A, const float* __restrict__ B,
    float* __restrict__ C, int M,
    const int* __restrict__ rows, int* __restrict__ row_ptr) {
    __shared__ float As[32][68];    // [k][m], padded
    __shared__ float Bs[32][128];   // [k][n], quad-swizzled

    const int tid = threadIdx.x;

    if (blockIdx.x >= GEMM_BLOCKS) {
        // ---- fused rowptr: binary search, no LDS, no barriers.
        int i = (blockIdx.x - GEMM_BLOCKS) * 128 + tid;
        if (i <= N_NODES) {
            int lo = 0, hi = N_EDGES;
            while (lo < hi) {
                int mid = (lo + hi) >> 1;
                if (rows[mid] < i) lo = mid + 1; else hi = mid;
            }
            row_ptr[i] = lo;
        }
        return;
    }

    const int tx = tid & 15;   // n0 = tx*8
    const int ty = tid >> 4;   // m0 = ty*8  (0..7)
    const int block_m = blockIdx.x * 64;

    const int bq0 = bswz(2 * tx) * 4;
    const int bq1 = bswz(2 * tx + 1) * 4;

    float acc[8][8];
#pragma unroll
    for (int i = 0; i < 8; i++)
#pragma unroll
        for (int j = 0; j < 8; j++) acc[i][j] = 0.0f;

    for (int k0 = 0; k0 < IN_FEAT; k0 += 32) {
        // Stage A tile: 64 rows x 32 k = 512 float4 / 128 threads = 4 each.
#pragma unroll
        for (int i = 0; i < 4; i++) {
            int f = tid + i * 128;
            int r = f >> 3;
            int kq = (f & 7) << 2;
            int gm = block_m + r;
            float4 v = make_float4(0.f, 0.f, 0.f, 0.f);
            if (gm < M) v = *(const float4*)(A + (size_t)gm * IN_FEAT + k0 + kq);
            As[kq + 0][r] = v.x;
            As[kq + 1][r] = v.y;
            As[kq + 2][r] = v.z;
            As[kq + 3][r] = v.w;
        }
        // Stage B tile: 32 rows x 128 n = 1024 float4 / 128 threads = 8 each.
#pragma unroll
        for (int i = 0; i < 8; i++) {
            int f = tid + i * 128;
            int r = f >> 5;
            int q = f & 31;
            *(float4*)&Bs[r][bswz(q) * 4] =
                *(const float4*)(B + (size_t)(k0 + r) * OUT_FEAT + q * 4);
        }
        __syncthreads();

#pragma unroll
        for (int k = 0; k < 32; k++) {
            float4 a0 = *(const float4*)&As[k][ty * 8];
            float4 a1 = *(const float4*)&As[k][ty * 8 + 4];
            float4 b0 = *(const float4*)&Bs[k][bq0];
            float4 b1 = *(const float4*)&Bs[k][bq1];
            float av[8] = {a0.x, a0.y, a0.z, a0.w, a1.x, a1.y, a1.z, a1.w};
            float bv[8] = {b0.x, b0.y, b0.z, b0.w, b1.x, b1.y, b1.z, b1.w};
#pragma unroll
            for (int i = 0; i < 8; i++)
#pragma unroll
                for (int j = 0; j < 8; j++)
                    acc[i][j] = fmaf(av[i], bv[j], acc[i][j]);
        }
        __syncthreads();
    }

#pragma unroll
    for (int i = 0; i < 8; i++) {
        int gm = block_m + ty * 8 + i;
        if (gm < M) {
            float* cp = C + (size_t)gm * OUT_FEAT + tx * 8;
            *(float4*)cp = make_float4(acc[i][0], acc[i][1], acc[i][2], acc[i][3]);
            *(float4*)(cp + 4) = make_float4(acc[i][4], acc[i][5], acc[i][6], acc[i][7]);
        }
    }
}

// ---------------------------------------------------------------------------
// SPMM + multispike: one wave per output row, lane l owns float2 l of the
// 128-float row.
// R9: pipeline deepened 8 -> 16 edges per iteration (regime probe: doubles
// per-wave outstanding gather bytes; helps iff spmm is wave-MLP/latency
// bound, neutral if TCP-queue/fabric-BW bound). All 16 idx/weight loads
// issue first, then 16 independent gathers, then ONE strict e-order FMA
// chain. Padded slots (clamped index, w=0) are bit-exact no-ops. Arrays
// statically indexed (fully unrolled) -> registers, ~80 VGPR, no spill.
// ---------------------------------------------------------------------------
__global__ __launch_bounds__(256) void spmm_kernel(const float* __restrict__ x,
                                                   const int* __restrict__ cols,
                                                   const float* __restrict__ ew,
                                                   const int* __restrict__ row_ptr,
                                                   float* __restrict__ out) {
    const int wave = threadIdx.x >> 6;
    const int lane = threadIdx.x & 63;
    const int r = blockIdx.x * 4 + wave;
    if (r >= N_NODES) return;

    const int e0 = row_ptr[r];
    const int e1 = row_ptr[r + 1];
    const int niter = (e1 - e0 + 15) >> 4;   // zero-padded to multiple of 16
    const float2* __restrict__ x2 = (const float2*)x;

    float accx = 0.0f, accy = 0.0f;

    for (int t = 0; t < niter; t++) {
        const int base = e0 + t * 16;
        int c[16];
        float w[16];
#pragma unroll
        for (int j = 0; j < 16; j++) {
            int e = base + j;
            int ee = (e < e1) ? e : (e1 - 1);
            c[j] = cols[ee];
            w[j] = (e < e1) ? ew[ee] : 0.0f;
        }
        float2 v[16];
#pragma unroll
        for (int j = 0; j < 16; j++) {
            v[j] = x2[(size_t)c[j] * 64 + lane];
        }
#pragma unroll
        for (int j = 0; j < 16; j++) {   // strict e-order accumulation
            accx = fmaf(w[j], v[j].x, accx);
            accy = fmaf(w[j], v[j].y, accy);
        }
    }

    float2* out2 = (float2*)out;
    out2[(size_t)r * 64 + lane] = make_float2(multispike(accx), multispike(accy));
}

extern "C" void kernel_launch(void* const* d_in, const int* in_sizes, int n_in,
                              void* d_out, int out_size, void* d_ws, size_t ws_size,
                              hipStream_t stream) {
    const float* feat = (const float*)d_in[0];   // [50000, 512]
    const float* weight = (const float*)d_in[1]; // [512, 128]
    const int* rows = (const int*)d_in[2];       // [800000] sorted
    const int* cols = (const int*)d_in[3];       // [800000]
    const float* ew = (const float*)d_in[4];     // [800000]
    float* out = (float*)d_out;                  // [50000, 128]

    // Workspace layout: x [50000*128 f32] then row_ptr [50001 i32]
    float* x = (float*)d_ws;
    int* row_ptr = (int*)((char*)d_ws + (size_t)N_NODES * OUT_FEAT * sizeof(float));

    gemm_rowptr_kernel<<<GEMM_BLOCKS + ROWPTR_BLOCKS, 128, 0, stream>>>(
        feat, weight, x, N_NODES, rows, row_ptr);
    spmm_kernel<<<(N_NODES + 3) / 4, 256, 0, stream>>>(x, cols, ew, row_ptr, out);
}

// Round 6
// 311.498 us; speedup vs baseline: 1.2976x; 1.0034x over previous
//
#include <hip/hip_runtime.h>

#define N_NODES 50000
#define N_EDGES 800000
#define IN_FEAT 512
#define OUT_FEAT 128

#define GEMM_BLOCKS ((N_NODES + 31) / 32)            // 1563 (BM=32)
#define ROWPTR_BLOCKS ((N_NODES + 1 + 127) / 128)    // 391 blocks of 128 thr

// NUMERICS CONTRACT (R3 post-mortem): the harness's np reference is matched
// bit-for-bit through the multispike quantizer ONLY when fp32 accumulation
// order is strictly sequential (k-order in GEMM, edge-order in SPMM).
// Reassociating a sum flipped a floor() boundary -> absmax 0.25. Do NOT
// split accumulator chains. Zero-padding with w=0 is safe: fmaf(0,v,acc)
// == acc bit-exactly for finite v.
//
// R5/R6 HARD RULE: no multi-float4 register array held across a loop
// boundary alongside the accumulators (spills).
// R7: in-block pipelining schemes (reg-prefetch, A-direct, DMA dbuf) all
// lost to the plain 2-barrier loop; cross-block overlap is the only
// latency-hiding that has ever worked here.
// R9: spmm regime probe (8->16 deep MLP) NEUTRAL -> spmm is fabric-BW
// bound at ~3 TB/s on 410MB of irreducible gather traffic. spmm FROZEN.
// R10: gemm was grid-starved (782 blocks = 3.05/CU, occupancy 15%, ~11k
// cyc/chunk exposed staging latency). BM 64->32: grid 1563 = 6.1
// blocks/CU, cross-block overlap hides staging. Per-(m,n) k-chain
// unchanged -> bit-exact.

__device__ __forceinline__ float multispike(float a) {
    // floor(clamp(4x, 0, 4) + 0.5) / 4
    return floorf(fminf(fmaxf(4.0f * a, 0.0f), 4.0f) + 0.5f) * 0.25f;
}

// ---------------------------------------------------------------------------
// GEMM: C[M,128] = A[M,512] @ B[512,128], fp32 vector FMA.
// BM=32, BN=128, BK=32. 128 threads (2 waves). Thread tile 4x8.
// Blocks [0, GEMM_BLOCKS): gemm. [GEMM_BLOCKS, +ROWPTR_BLOCKS): fused
// row_ptr binary search (no LDS, no barriers, exits early -> no hazard).
// - As[32][36]: transposed store, pad 36 keeps rows 16B-aligned for b128
//   reads; store conflict 4-way (same as R4's 68-pad; acceptable).
// - A-read: ty*4 offsets {0,4,8,12} floats across wave -> 4 distinct bank
//   quads, conflict-free, 16-lane broadcast.
// - Bs XOR quad-swizzle bswz(q)=q^((q>>3)&1) on store and load (R4-
//   verified: 128B-stride aliasing 2-way = free).
// ---------------------------------------------------------------------------
__device__ __forceinline__ int bswz(int q) { return q ^ ((q >> 3) & 1); }

__global__ __launch_bounds__(128) void gemm_rowptr_kernel(
    const float* __restrict__ A, const float* __restrict__ B,
    float* __restrict__ C, int M,
    const int* __restrict__ rows, int* __restrict__ row_ptr) {
    __shared__ float As[32][36];    // [k][m], padded
    __shared__ float Bs[32][128];   // [k][n], quad-swizzled

    const int tid = threadIdx.x;

    if (blockIdx.x >= GEMM_BLOCKS) {
        // ---- fused rowptr: binary search, no LDS, no barriers.
        int i = (blockIdx.x - GEMM_BLOCKS) * 128 + tid;
        if (i <= N_NODES) {
            int lo = 0, hi = N_EDGES;
            while (lo < hi) {
                int mid = (lo + hi) >> 1;
                if (rows[mid] < i) lo = mid + 1; else hi = mid;
            }
            row_ptr[i] = lo;
        }
        return;
    }

    const int tx = tid & 15;   // n0 = tx*8
    const int ty = tid >> 4;   // 0..7, m0 = ty*4
    const int block_m = blockIdx.x * 32;

    const int bq0 = bswz(2 * tx) * 4;
    const int bq1 = bswz(2 * tx + 1) * 4;

    float acc[4][8];
#pragma unroll
    for (int i = 0; i < 4; i++)
#pragma unroll
        for (int j = 0; j < 8; j++) acc[i][j] = 0.0f;

    for (int k0 = 0; k0 < IN_FEAT; k0 += 32) {
        // Stage A tile: 32 rows x 32 k = 256 float4 / 128 threads = 2 each.
#pragma unroll
        for (int i = 0; i < 2; i++) {
            int f = tid + i * 128;
            int r = f >> 3;             // 0..31
            int kq = (f & 7) << 2;
            int gm = block_m + r;
            float4 v = make_float4(0.f, 0.f, 0.f, 0.f);
            if (gm < M) v = *(const float4*)(A + (size_t)gm * IN_FEAT + k0 + kq);
            As[kq + 0][r] = v.x;
            As[kq + 1][r] = v.y;
            As[kq + 2][r] = v.z;
            As[kq + 3][r] = v.w;
        }
        // Stage B tile: 32 rows x 128 n = 1024 float4 / 128 threads = 8 each.
#pragma unroll
        for (int i = 0; i < 8; i++) {
            int f = tid + i * 128;
            int r = f >> 5;
            int q = f & 31;
            *(float4*)&Bs[r][bswz(q) * 4] =
                *(const float4*)(B + (size_t)(k0 + r) * OUT_FEAT + q * 4);
        }
        __syncthreads();

#pragma unroll
        for (int k = 0; k < 32; k++) {
            float4 a0 = *(const float4*)&As[k][ty * 4];
            float4 b0 = *(const float4*)&Bs[k][bq0];
            float4 b1 = *(const float4*)&Bs[k][bq1];
            float av[4] = {a0.x, a0.y, a0.z, a0.w};
            float bv[8] = {b0.x, b0.y, b0.z, b0.w, b1.x, b1.y, b1.z, b1.w};
#pragma unroll
            for (int i = 0; i < 4; i++)
#pragma unroll
                for (int j = 0; j < 8; j++)
                    acc[i][j] = fmaf(av[i], bv[j], acc[i][j]);
        }
        __syncthreads();
    }

#pragma unroll
    for (int i = 0; i < 4; i++) {
        int gm = block_m + ty * 4 + i;
        if (gm < M) {
            float* cp = C + (size_t)gm * OUT_FEAT + tx * 8;
            *(float4*)cp = make_float4(acc[i][0], acc[i][1], acc[i][2], acc[i][3]);
            *(float4*)(cp + 4) = make_float4(acc[i][4], acc[i][5], acc[i][6], acc[i][7]);
        }
    }
}

// ---------------------------------------------------------------------------
// SPMM + multispike (FROZEN, R9): one wave per output row, lane l owns
// float2 l. 16-deep gather pipeline, zero-padded (w=0 slots are bit-exact
// no-ops), ONE strict e-order FMA chain per accumulator.
// ---------------------------------------------------------------------------
__global__ __launch_bounds__(256) void spmm_kernel(const float* __restrict__ x,
                                                   const int* __restrict__ cols,
                                                   const float* __restrict__ ew,
                                                   const int* __restrict__ row_ptr,
                                                   float* __restrict__ out) {
    const int wave = threadIdx.x >> 6;
    const int lane = threadIdx.x & 63;
    const int r = blockIdx.x * 4 + wave;
    if (r >= N_NODES) return;

    const int e0 = row_ptr[r];
    const int e1 = row_ptr[r + 1];
    const int niter = (e1 - e0 + 15) >> 4;   // zero-padded to multiple of 16
    const float2* __restrict__ x2 = (const float2*)x;

    float accx = 0.0f, accy = 0.0f;

    for (int t = 0; t < niter; t++) {
        const int base = e0 + t * 16;
        int c[16];
        float w[16];
#pragma unroll
        for (int j = 0; j < 16; j++) {
            int e = base + j;
            int ee = (e < e1) ? e : (e1 - 1);
            c[j] = cols[ee];
            w[j] = (e < e1) ? ew[ee] : 0.0f;
        }
        float2 v[16];
#pragma unroll
        for (int j = 0; j < 16; j++) {
            v[j] = x2[(size_t)c[j] * 64 + lane];
        }
#pragma unroll
        for (int j = 0; j < 16; j++) {   // strict e-order accumulation
            accx = fmaf(w[j], v[j].x, accx);
            accy = fmaf(w[j], v[j].y, accy);
        }
    }

    float2* out2 = (float2*)out;
    out2[(size_t)r * 64 + lane] = make_float2(multispike(accx), multispike(accy));
}

extern "C" void kernel_launch(void* const* d_in, const int* in_sizes, int n_in,
                              void* d_out, int out_size, void* d_ws, size_t ws_size,
                              hipStream_t stream) {
    const float* feat = (const float*)d_in[0];   // [50000, 512]
    const float* weight = (const float*)d_in[1]; // [512, 128]
    const int* rows = (const int*)d_in[2];       // [800000] sorted
    const int* cols = (const int*)d_in[3];       // [800000]
    const float* ew = (const float*)d_in[4];     // [800000]
    float* out = (float*)d_out;                  // [50000, 128]

    // Workspace layout: x [50000*128 f32] then row_ptr [50001 i32]
    float* x = (float*)d_ws;
    int* row_ptr = (int*)((char*)d_ws + (size_t)N_NODES * OUT_FEAT * sizeof(float));

    gemm_rowptr_kernel<<<GEMM_BLOCKS + ROWPTR_BLOCKS, 128, 0, stream>>>(
        feat, weight, x, N_NODES, rows, row_ptr);
    spmm_kernel<<<(N_NODES + 3) / 4, 256, 0, stream>>>(x, cols, ew, row_ptr, out);
}